// Round 4
// baseline (3610.585 us; speedup 1.0000x reference)
//
#include <hip/hip_runtime.h>
#include <stdint.h>

// Forbid mul+add contraction: distance arithmetic must match the numpy
// reference bit-for-bit (argmax / radius-compare are discontinuous).
// MLP math uses explicit fmaf() (exact FMA is fine; only ordering matters).
#pragma clang fp contract(off)

#define NPT   16384
#define BB    8
#define SS    1024
#define KSAMP 32
#define PTOT  (BB*SS*KSAMP)   // 262144
#define NGRP  (BB*SS)         // 8192
#define R2    0.04f
#define EPSBN 1e-5f
#define INV_M 3.814697265625e-06f   // 1/262144, exact power of two

// ws layout (floats)
#define OFF_S1 0
#define OFF_Q1 64
#define OFF_S2 128
#define OFF_Q2 192
#define OFF_S3 256    // 128
#define OFF_Q3 384    // 128
#define OFF_A1 512
#define OFF_C1 576
#define OFF_A2 640
#define OFF_C2 704
#define OFF_A3 768    // 128
#define OFF_C3 896    // 128
#define OFF_ZMAX 1024                  // 8192*128 = 1048576
#define OFF_FEAT (1024 + 1048576)      // 6*262144 = 1572864  (total ~10.5 MB)

// ---------------------------------------------------------------------------
// helpers
// ---------------------------------------------------------------------------
__device__ __forceinline__ float wave_sum(float v) {
#pragma unroll
  for (int off = 32; off; off >>= 1) v += __shfl_xor(v, off);
  return v;  // butterfly: all lanes hold identical total
}
__device__ __forceinline__ float half_max(float v) {
#pragma unroll
  for (int off = 16; off; off >>= 1) v = fmaxf(v, __shfl_xor(v, off));
  return v;  // max within each 32-lane half
}

// ---------------------------------------------------------------------------
// 1) Farthest point sampling: one block per batch, 1024 thr x 16 pts/thread.
//    KEY FIX vs R2/R3 (both VGPR=84, 2.3ms): pointers are NOT __restrict__.
//    The loop stores to newxyz every iteration; without restrict the compiler
//    cannot prove those stores don't alias xyz, so rematerializing the
//    coordinate loads inside the loop is ILLEGAL -> x/y/z must stay live in
//    registers. 16 pts/thread keeps pressure at ~90 VGPR, far under the 128
//    cap of (1024,4) -> no spill. R2's failure mode (192 KB/iter re-streamed
//    from L2, 2.29us/iter) is structurally impossible here.
//    Arithmetic order identical to R2/R3 (bit-exact vs numpy, passed 3x).
// ---------------------------------------------------------------------------
__global__ __launch_bounds__(1024, 4)
void fps_kernel(const float* xyz, float* newxyz) {
  const int b = blockIdx.x;
  const int t = threadIdx.x;
  const int lane = t & 63;
  const int w = t >> 6;                 // 16 waves
  const float* xb = xyz + (size_t)b * NPT * 3;

  float x[16], y[16], z[16], d[16];
#pragma unroll
  for (int j = 0; j < 16; ++j) {
    int p = j * 1024 + t;               // ascending point index in j
    x[j] = xb[3 * p];
    y[j] = xb[3 * p + 1];
    z[j] = xb[3 * p + 2];
    d[j] = 1e10f;
  }

  __shared__ float rv[2][16];
  __shared__ int   ri[2][16];

  int fi = 0;                            // current centroid index (uniform)
  if (t == 0) {
    float* o = newxyz + (size_t)b * SS * 3;   // idx[0] = 0
    o[0] = xb[0]; o[1] = xb[1]; o[2] = xb[2];
  }

  for (int it = 1; it < SS; ++it) {
    // all lanes load the centroid (same address -> L1 broadcast)
    float cx = xb[3 * fi], cy = xb[3 * fi + 1], cz = xb[3 * fi + 2];
    float bv = -1.0f; int bi = 0x7fffffff;
#pragma unroll
    for (int j = 0; j < 16; ++j) {
      float dx = x[j] - cx, dy = y[j] - cy, dz = z[j] - cz;
      float d2 = (dx * dx + dy * dy) + dz * dz;   // matches numpy order
      float dm = fminf(d[j], d2);
      d[j] = dm;
      if (dm > bv) { bv = dm; bi = j * 1024 + t; } // strict > keeps lowest j
    }
#pragma unroll
    for (int off = 32; off >= 1; off >>= 1) {     // wave argmax, tie->low idx
      float ov = __shfl_xor(bv, off);
      int   oi = __shfl_xor(bi, off);
      if (ov > bv || (ov == bv && oi < bi)) { bv = ov; bi = oi; }
    }
    const int buf = it & 1;
    if (lane == 0) { rv[buf][w] = bv; ri[buf][w] = bi; }
    __syncthreads();
    // single barrier: next iteration writes the OTHER buffer, and its own
    // barrier orders those writes after these reads.
    float fv = rv[buf][0]; fi = ri[buf][0];
#pragma unroll
    for (int ww = 1; ww < 16; ++ww) {
      float ov = rv[buf][ww]; int oi = ri[buf][ww];
      if (ov > fv || (ov == fv && oi < fi)) { fv = ov; fi = oi; }
    }
    if (t == 0) {
      float* o = newxyz + ((size_t)b * SS + it) * 3;
      o[0] = xb[3 * fi]; o[1] = xb[3 * fi + 1]; o[2] = xb[3 * fi + 2];
    }
  }
}

// ---------------------------------------------------------------------------
// 2) Ball query + gather (fused): one wave per centroid, ascending-index scan
//    with ballot == ref's sort+slice. feat is channel-major [6][PTOT].
// ---------------------------------------------------------------------------
__global__ __launch_bounds__(256, 2)
void ballq_kernel(const float* __restrict__ xyz, const float* __restrict__ pts,
                  const float* __restrict__ newxyz, float* __restrict__ feat) {
  const int lane = threadIdx.x & 63;
  const int c = blockIdx.x * 4 + (threadIdx.x >> 6);  // 0..8191
  const int b = c >> 10;
  const float* xb = xyz + (size_t)b * NPT * 3;
  const float* pb = pts + (size_t)b * NPT * 3;
  const float cx = newxyz[3 * c], cy = newxyz[3 * c + 1], cz = newxyz[3 * c + 2];
  const int base = c * KSAMP;
  const uint64_t ltm = (1ull << lane) - 1ull;

  int cnt = 0, firstp = 0;
  bool haveFirst = false;
  for (int p0 = 0; p0 < NPT && cnt < KSAMP; p0 += 64) {
    int p = p0 + lane;
    float px = xb[3 * p], py = xb[3 * p + 1], pz = xb[3 * p + 2];
    float dx = cx - px, dy = cy - py, dz = cz - pz;
    float sqr = (dx * dx + dy * dy) + dz * dz;
    bool in = (sqr <= R2);                          // !(sqr > r^2)
    uint64_t m = __ballot(in);
    if (!haveFirst && m) { firstp = p0 + (__ffsll((unsigned long long)m) - 1); haveFirst = true; }
    int rank = (int)__popcll(m & ltm);
    int slot = cnt + rank;
    if (in && slot < KSAMP) {
      int idx = base + slot;
      feat[0 * PTOT + idx] = px - cx;
      feat[1 * PTOT + idx] = py - cy;
      feat[2 * PTOT + idx] = pz - cz;
      feat[3 * PTOT + idx] = pb[3 * p];
      feat[4 * PTOT + idx] = pb[3 * p + 1];
      feat[5 * PTOT + idx] = pb[3 * p + 2];
    }
    cnt += (int)__popcll(m);
  }
  if (cnt < KSAMP) {  // pad with first in-ball point (center itself qualifies)
    int slot = cnt + lane;
    if (slot < KSAMP) {
      int idx = base + slot;
      float px = xb[3 * firstp], py = xb[3 * firstp + 1], pz = xb[3 * firstp + 2];
      feat[0 * PTOT + idx] = px - cx;
      feat[1 * PTOT + idx] = py - cy;
      feat[2 * PTOT + idx] = pz - cz;
      feat[3 * PTOT + idx] = pb[3 * firstp];
      feat[4 * PTOT + idx] = pb[3 * firstp + 1];
      feat[5 * PTOT + idx] = pb[3 * firstp + 2];
    }
  }
}

// ---------------------------------------------------------------------------
// 3) stats of layer-1 pre-activations. Per-thread s[64],q[64] (cheap here:
//    only 6 FMA per channel). Block-reduce -> global atomics.
// ---------------------------------------------------------------------------
__global__ __launch_bounds__(256, 2)
void mlp1s_kernel(const float* __restrict__ feat, const float* __restrict__ w0,
                  const float* __restrict__ b0, float* __restrict__ stats) {
  float s[64], q[64];
#pragma unroll
  for (int o = 0; o < 64; ++o) { s[o] = 0.0f; q[o] = 0.0f; }
  int gid = blockIdx.x * 256 + threadIdx.x;
  for (int p = gid; p < PTOT; p += 256 * 256) {
    float f[6];
#pragma unroll
    for (int ch = 0; ch < 6; ++ch) f[ch] = feat[ch * PTOT + p];
#pragma unroll
    for (int o = 0; o < 64; ++o) {
      float z = b0[o];
#pragma unroll
      for (int i = 0; i < 6; ++i) z = fmaf(w0[o * 6 + i], f[i], z);
      s[o] += z; q[o] = fmaf(z, z, q[o]);
    }
  }
  const int lane = threadIdx.x & 63;
#pragma unroll
  for (int o = 0; o < 64; ++o) { s[o] = wave_sum(s[o]); q[o] = wave_sum(q[o]); }
  __shared__ float ls[128];
  if (threadIdx.x < 128) ls[threadIdx.x] = 0.0f;
  __syncthreads();
  if (lane == 0) {
#pragma unroll
    for (int o = 0; o < 64; ++o) { atomicAdd(&ls[o], s[o]); atomicAdd(&ls[64 + o], q[o]); }
  }
  __syncthreads();
  if (threadIdx.x < 64) atomicAdd(&stats[OFF_S1 + threadIdx.x], ls[threadIdx.x]);
  else if (threadIdx.x < 128) atomicAdd(&stats[OFF_Q1 + threadIdx.x - 64], ls[threadIdx.x]);
}

// ---------------------------------------------------------------------------
// BN fold: a = g/sqrt(var+eps), c = be - a*mu   (h = relu(a*z + c))
// ---------------------------------------------------------------------------
__global__ void fin_kernel(const float* __restrict__ g, const float* __restrict__ be,
                           const float* __restrict__ s, const float* __restrict__ q,
                           float* __restrict__ A, float* __restrict__ C, int Cn) {
  int o = blockIdx.x * blockDim.x + threadIdx.x;
  if (o >= Cn) return;
  float mu = s[o] * INV_M;
  float var = q[o] * INV_M - mu * mu;
  float a = g[o] / sqrtf(var + EPSBN);
  A[o] = a;
  C[o] = be[o] - a * mu;
}

// ---------------------------------------------------------------------------
// 4) stats of layer-2 pre-activations. h1 built explicitly (unrolled o),
//    then rolled-o loop: scalar z2 accumulators + wave-butterfly stats into
//    designated-lane registers.
// ---------------------------------------------------------------------------
__global__ __launch_bounds__(256, 2)
void mlp2s_kernel(const float* __restrict__ feat,
                  const float* __restrict__ w0, const float* __restrict__ b0,
                  const float* __restrict__ w1, const float* __restrict__ b1,
                  const float* __restrict__ par, float* __restrict__ stats) {
  const float* a1 = par + OFF_A1;
  const float* c1 = par + OFF_C1;
  const int lane = threadIdx.x & 63;
  float sp = 0.0f, qp = 0.0f;          // this lane's channel (== lane)
  int gid = blockIdx.x * 256 + threadIdx.x;
  for (int p = gid; p < PTOT; p += 512 * 256) {
    float f[6];
#pragma unroll
    for (int ch = 0; ch < 6; ++ch) f[ch] = feat[ch * PTOT + p];
    float h1[64];
#pragma unroll
    for (int o = 0; o < 64; ++o) {
      float z = b0[o];
#pragma unroll
      for (int i = 0; i < 6; ++i) z = fmaf(w0[o * 6 + i], f[i], z);
      h1[o] = fmaxf(fmaf(a1[o], z, c1[o]), 0.0f);
    }
    for (int o = 0; o < 64; o += 2) {   // rolled: scalar temps only
      float z0 = b1[o], z1 = b1[o + 1];
#pragma unroll
      for (int i = 0; i < 64; ++i) {
        z0 = fmaf(w1[o * 64 + i], h1[i], z0);
        z1 = fmaf(w1[(o + 1) * 64 + i], h1[i], z1);
      }
      float s0 = wave_sum(z0), q0 = wave_sum(z0 * z0);
      float s1 = wave_sum(z1), q1 = wave_sum(z1 * z1);
      if (lane == o)     { sp += s0; qp += q0; }
      if (lane == o + 1) { sp += s1; qp += q1; }
    }
  }
  atomicAdd(&stats[OFF_S2 + lane], sp);
  atomicAdd(&stats[OFF_Q2 + lane], qp);
}

// ---------------------------------------------------------------------------
// 5) layer-3 fused: recompute h1 (per-i, no array), accumulate h2[64]
//    (i-rolled, o-unrolled), then rolled-o layer-3 with butterfly stats +
//    half-wave max. Writes zmax[g][o] (raw pre-BN max; valid because a3>0
//    makes relu(a*z+c) monotone).
// ---------------------------------------------------------------------------
__global__ __launch_bounds__(256, 2)
void mlp3f_kernel(const float* __restrict__ feat,
                  const float* __restrict__ w0, const float* __restrict__ b0,
                  const float* __restrict__ w1, const float* __restrict__ b1,
                  const float* __restrict__ w2, const float* __restrict__ b2,
                  const float* __restrict__ par, float* __restrict__ stats,
                  float* __restrict__ zmax) {
  const float* a1 = par + OFF_A1;
  const float* c1 = par + OFF_C1;
  const float* a2 = par + OFF_A2;
  const float* c2 = par + OFF_C2;
  const int lane = threadIdx.x & 63;
  float sp0 = 0.0f, qp0 = 0.0f;        // channel lane
  float sp1 = 0.0f, qp1 = 0.0f;        // channel 64+lane
  int gid = blockIdx.x * 256 + threadIdx.x;
  for (int p = gid; p < PTOT; p += 512 * 256) {
    float f[6];
#pragma unroll
    for (int ch = 0; ch < 6; ++ch) f[ch] = feat[ch * PTOT + p];
    float h2[64];
#pragma unroll
    for (int o = 0; o < 64; ++o) h2[o] = b1[o];
    for (int i = 0; i < 64; ++i) {      // rolled; h1[i] recomputed (8 instr)
      float z = b0[i];
#pragma unroll
      for (int ch = 0; ch < 6; ++ch) z = fmaf(w0[i * 6 + ch], f[ch], z);
      float h1i = fmaxf(fmaf(a1[i], z, c1[i]), 0.0f);
#pragma unroll
      for (int o = 0; o < 64; ++o) h2[o] = fmaf(w1[o * 64 + i], h1i, h2[o]);
    }
#pragma unroll
    for (int o = 0; o < 64; ++o) h2[o] = fmaxf(fmaf(a2[o], h2[o], c2[o]), 0.0f);

    const int g = p >> 5;               // this lane's group
    for (int o = 0; o < 128; o += 2) {  // rolled: scalar temps
      float z0 = b2[o], z1 = b2[o + 1];
#pragma unroll
      for (int i = 0; i < 64; ++i) {
        z0 = fmaf(w2[o * 64 + i], h2[i], z0);
        z1 = fmaf(w2[(o + 1) * 64 + i], h2[i], z1);
      }
      float s0 = wave_sum(z0), q0 = wave_sum(z0 * z0);
      float s1 = wave_sum(z1), q1 = wave_sum(z1 * z1);
      if (lane == (o & 63))       { if (o < 64) { sp0 += s0; qp0 += q0; } else { sp1 += s0; qp1 += q0; } }
      if (lane == ((o + 1) & 63)) { if (o < 64) { sp0 += s1; qp0 += q1; } else { sp1 += s1; qp1 += q1; } }
      float m0 = half_max(z0), m1 = half_max(z1);
      if ((lane & 31) == (o & 31))       zmax[g * 128 + o]     = m0;
      if ((lane & 31) == ((o + 1) & 31)) zmax[g * 128 + o + 1] = m1;
    }
  }
  atomicAdd(&stats[OFF_S3 + lane], sp0);
  atomicAdd(&stats[OFF_Q3 + lane], qp0);
  atomicAdd(&stats[OFF_S3 + 64 + lane], sp1);
  atomicAdd(&stats[OFF_Q3 + 64 + lane], qp1);
}

// ---------------------------------------------------------------------------
// 6) epilogue: out2[g][c] = relu(a3[c]*zmax[g][c] + c3[c])
// ---------------------------------------------------------------------------
__global__ __launch_bounds__(256, 4)
void final_out_kernel(const float* __restrict__ zmax, const float* __restrict__ par,
                      float* __restrict__ out2) {
  const float* a3 = par + OFF_A3;
  const float* c3 = par + OFF_C3;
  int idx = blockIdx.x * 256 + threadIdx.x;   // g*128 + c
  int c = idx & 127;
  out2[idx] = fmaxf(fmaf(a3[c], zmax[idx], c3[c]), 0.0f);
}

// ---------------------------------------------------------------------------
extern "C" void kernel_launch(void* const* d_in, const int* in_sizes, int n_in,
                              void* d_out, int out_size, void* d_ws, size_t ws_size,
                              hipStream_t stream) {
  const float* xyz = (const float*)d_in[0];
  const float* pts = (const float*)d_in[1];
  const float* w0  = (const float*)d_in[2];
  const float* b0  = (const float*)d_in[3];
  const float* g0  = (const float*)d_in[4];
  const float* be0 = (const float*)d_in[5];
  const float* w1  = (const float*)d_in[6];
  const float* b1  = (const float*)d_in[7];
  const float* g1  = (const float*)d_in[8];
  const float* be1 = (const float*)d_in[9];
  const float* w2  = (const float*)d_in[10];
  const float* b2  = (const float*)d_in[11];
  const float* g2  = (const float*)d_in[12];
  const float* be2 = (const float*)d_in[13];

  float* out  = (float*)d_out;
  float* nxz  = out;                 // (B,S,3)
  float* out2 = out + BB * SS * 3;   // (B,S,128)

  float* ws    = (float*)d_ws;
  float* stats = ws;                 // 512 floats, zeroed every call
  float* par   = ws;                 // params addressed via OFF_* macros
  float* zmax  = ws + OFF_ZMAX;
  float* feat  = ws + OFF_FEAT;

  hipMemsetAsync(stats, 0, 512 * sizeof(float), stream);

  fps_kernel<<<BB, 1024, 0, stream>>>(xyz, nxz);
  ballq_kernel<<<2048, 256, 0, stream>>>(xyz, pts, nxz, feat);

  mlp1s_kernel<<<256, 256, 0, stream>>>(feat, w0, b0, stats);
  fin_kernel<<<1, 64, 0, stream>>>(g0, be0, stats + OFF_S1, stats + OFF_Q1,
                                   par + OFF_A1, par + OFF_C1, 64);
  mlp2s_kernel<<<512, 256, 0, stream>>>(feat, w0, b0, w1, b1, par, stats);
  fin_kernel<<<1, 64, 0, stream>>>(g1, be1, stats + OFF_S2, stats + OFF_Q2,
                                   par + OFF_A2, par + OFF_C2, 64);
  mlp3f_kernel<<<512, 256, 0, stream>>>(feat, w0, b0, w1, b1, w2, b2, par, stats, zmax);
  fin_kernel<<<1, 128, 0, stream>>>(g2, be2, stats + OFF_S3, stats + OFF_Q3,
                                    par + OFF_A3, par + OFF_C3, 128);
  final_out_kernel<<<4096, 256, 0, stream>>>(zmax, par, out2);
}

// Round 5
// 3497.209 us; speedup vs baseline: 1.0324x; 1.0324x over previous
//
#include <hip/hip_runtime.h>
#include <stdint.h>

// Forbid mul+add contraction: distance arithmetic must match the numpy
// reference bit-for-bit (argmax / radius-compare are discontinuous).
// MLP math uses explicit fmaf() (exact FMA is fine; only ordering matters).
#pragma clang fp contract(off)

#define NPT   16384
#define BB    8
#define SS    1024
#define KSAMP 32
#define PTOT  (BB*SS*KSAMP)   // 262144
#define NGRP  (BB*SS)         // 8192
#define R2    0.04f
#define EPSBN 1e-5f
#define INV_M 3.814697265625e-06f   // 1/262144, exact power of two

// ws layout (floats)
#define OFF_S1 0
#define OFF_Q1 64
#define OFF_S2 128
#define OFF_Q2 192
#define OFF_S3 256    // 128
#define OFF_Q3 384    // 128
#define OFF_A1 512
#define OFF_C1 576
#define OFF_A2 640
#define OFF_C2 704
#define OFF_A3 768    // 128
#define OFF_C3 896    // 128
#define OFF_ZMAX 1024                  // 8192*128 = 1048576
#define OFF_FEAT (1024 + 1048576)      // 6*262144 = 1572864  (total ~10.5 MB)
// fps binned-point scratch ALIASES the feat region (2 MB of its 6 MB): fps
// finishes before ballq writes feat, so no extra ws is needed.

// ---------------------------------------------------------------------------
// helpers
// ---------------------------------------------------------------------------
__device__ __forceinline__ float wave_sum(float v) {
#pragma unroll
  for (int off = 32; off; off >>= 1) v += __shfl_xor(v, off);
  return v;  // butterfly: all lanes hold identical total
}
__device__ __forceinline__ float half_max(float v) {
#pragma unroll
  for (int off = 16; off; off >>= 1) v = fmaxf(v, __shfl_xor(v, off));
  return v;  // max within each 32-lane half
}

// ---------------------------------------------------------------------------
// 1) Farthest point sampling, EXACT + PRUNED. One block per batch.
//    R2-R4 post-mortem: brute force needs 16M point-updates on 8 CUs
//    (~650us floor) and the register allocator refuses to keep the cloud in
//    VGPRs (remat at VGPR=84 / scratch-spill at VGPR=48, both ~2.3-3.0ms).
//    Here: points binned into 8x8x8 buckets (avg 32 pts), d[] lives in LDS,
//    per-bucket bound = max(d) + first-orig-idx candidate. A bucket is
//    skipped iff distLB(c,bbox)^2 * 0.999 > bound  (conservative margin
//    covers all fp rounding; bbox is the exact member bounding box, so
//    distLB <= true distance). Skipped updates are provable no-ops under
//    exact fminf => d[] is BIT-IDENTICAL to brute force; argmax over
//    (value, orig idx) total order == numpy first-index argmax.
// ---------------------------------------------------------------------------
__global__ __launch_bounds__(1024, 4)
void fps_kernel(const float* __restrict__ xyz, float* __restrict__ newxyz,
                float4* __restrict__ bpt) {
  const int b = blockIdx.x;
  const int t = threadIdx.x;
  const int lane = t & 63;
  const int w = t >> 6;                 // 16 waves
  const float* xb = xyz + (size_t)b * NPT * 3;
  float4* bp = bpt + (size_t)b * NPT;

  __shared__ float dlds[NPT];                                   // 64 KB
  __shared__ float bminx[512], bminy[512], bminz[512];
  __shared__ float bmaxx[512], bmaxy[512], bmaxz[512];          // 12 KB
  __shared__ float bound[512];
  __shared__ int   cand[512];
  __shared__ int   cntb[512], startb[512], curb[512];
  __shared__ int   list[512];
  __shared__ float pv[8];
  __shared__ int   pi[8];
  __shared__ int   nact;

  // ---- setup: bin points into 8x8x8 cells (binning only affects speed;
  //      correctness comes from member-exact bboxes) ----
  if (t < 512) cntb[t] = 0;
  if (t == 0) nact = 0;
  __syncthreads();
  int mycell[16];
#pragma unroll
  for (int k = 0; k < 16; ++k) {
    int p = k * 1024 + t;
    float px = xb[3 * p], py = xb[3 * p + 1], pz = xb[3 * p + 2];
    int ix = min(7, max(0, (int)(px * 8.0f)));
    int iy = min(7, max(0, (int)(py * 8.0f)));
    int iz = min(7, max(0, (int)(pz * 8.0f)));
    int cell = (ix << 6) | (iy << 3) | iz;
    mycell[k] = cell;
    atomicAdd(&cntb[cell], 1);
  }
  __syncthreads();
  if (t == 0) {                         // serial scan: setup-only, cheap
    int acc = 0;
    for (int i = 0; i < 512; ++i) { startb[i] = acc; curb[i] = acc; acc += cntb[i]; }
  }
  __syncthreads();
#pragma unroll
  for (int k = 0; k < 16; ++k) {
    int p = k * 1024 + t;
    int pos = atomicAdd(&curb[mycell[k]], 1);
    bp[pos] = make_float4(xb[3 * p], xb[3 * p + 1], xb[3 * p + 2], __int_as_float(p));
  }
  for (int i = t; i < NPT; i += 1024) dlds[i] = 1e10f;
  __syncthreads();
  // member-exact bbox per bucket
  for (int bk = w; bk < 512; bk += 16) {
    int st = startb[bk], cn = cntb[bk];
    float mnx = 1e30f, mny = 1e30f, mnz = 1e30f;
    float mxx = -1e30f, mxy = -1e30f, mxz = -1e30f;
    for (int l = lane; l < cn; l += 64) {
      float4 q = bp[st + l];
      mnx = fminf(mnx, q.x); mny = fminf(mny, q.y); mnz = fminf(mnz, q.z);
      mxx = fmaxf(mxx, q.x); mxy = fmaxf(mxy, q.y); mxz = fmaxf(mxz, q.z);
    }
#pragma unroll
    for (int off = 32; off; off >>= 1) {
      mnx = fminf(mnx, __shfl_xor(mnx, off)); mny = fminf(mny, __shfl_xor(mny, off));
      mnz = fminf(mnz, __shfl_xor(mnz, off)); mxx = fmaxf(mxx, __shfl_xor(mxx, off));
      mxy = fmaxf(mxy, __shfl_xor(mxy, off)); mxz = fmaxf(mxz, __shfl_xor(mxz, off));
    }
    if (lane == 0) {
      bminx[bk] = mnx; bminy[bk] = mny; bminz[bk] = mnz;
      bmaxx[bk] = mxx; bmaxy[bk] = mxy; bmaxz[bk] = mxz;
      bound[bk] = (cn > 0) ? 1e10f : -1.0f;   // empty: never active/candidate
      cand[bk] = 0x7fffffff;
    }
  }
  if (t == 0) {                         // idx[0] = 0
    float* o = newxyz + (size_t)b * SS * 3;
    o[0] = xb[0]; o[1] = xb[1]; o[2] = xb[2];
  }
  __syncthreads();

  int fi = 0;                           // current centroid orig index (uniform)
  for (int it = 1; it < SS; ++it) {
    // all lanes: centroid coords (same address -> broadcast, L1-hot)
    float cx = xb[3 * fi], cy = xb[3 * fi + 1], cz = xb[3 * fi + 2];

    // ---- A: find active buckets, ballot-compact into list ----
    if (t < 512) {
      float lx = fmaxf(0.0f, fmaxf(bminx[t] - cx, cx - bmaxx[t]));
      float ly = fmaxf(0.0f, fmaxf(bminy[t] - cy, cy - bmaxy[t]));
      float lz = fmaxf(0.0f, fmaxf(bminz[t] - cz, cz - bmaxz[t]));
      float lb2 = (lx * lx + ly * ly) + lz * lz;
      bool ok = (lb2 * 0.999f <= bound[t]);   // conservative: process on ties
      uint64_t m = __ballot(ok);
      int cw = (int)__popcll(m);
      int base = 0;
      if (lane == 0 && cw) base = atomicAdd(&nact, cw);
      base = __shfl(base, 0);
      if (ok) list[base + (int)__popcll(m & ((1ull << lane) - 1ull))] = t;
    }
    __syncthreads();                    // bar1
    int na = nact;

    // ---- B: one wave per active bucket: update d, recompute bound/cand ----
    for (int a = w; a < na; a += 16) {
      int bk = list[a];
      int st = startb[bk], cn = cntb[bk];
      float v = -1.0f; int vi = 0x7fffffff;
      for (int l = lane; l < cn; l += 64) {
        float4 q = bp[st + l];
        float dx = q.x - cx, dy = q.y - cy, dz = q.z - cz;
        float d2 = (dx * dx + dy * dy) + dz * dz;   // numpy order, no fma
        float dn = fminf(dlds[st + l], d2);
        dlds[st + l] = dn;
        int oi = __float_as_int(q.w);
        if (dn > v || (dn == v && oi < vi)) { v = dn; vi = oi; }
      }
#pragma unroll
      for (int off = 32; off; off >>= 1) {
        float ov = __shfl_xor(v, off); int oi2 = __shfl_xor(vi, off);
        if (ov > v || (ov == v && oi2 < vi)) { v = ov; vi = oi2; }
      }
      if (lane == 0) { bound[bk] = v; cand[bk] = vi; }
    }
    __syncthreads();                    // bar2

    // ---- C: argmax over 512 bucket candidates ----
    if (w < 8) {
      float v = bound[t]; int vi = cand[t];
#pragma unroll
      for (int off = 32; off; off >>= 1) {
        float ov = __shfl_xor(v, off); int oi2 = __shfl_xor(vi, off);
        if (ov > v || (ov == v && oi2 < vi)) { v = ov; vi = oi2; }
      }
      if (lane == 0) { pv[w] = v; pi[w] = vi; }
    }
    if (t == 0) nact = 0;               // safe: read of na was before bar2
    __syncthreads();                    // bar3
    float fv = pv[0]; fi = pi[0];
#pragma unroll
    for (int ww = 1; ww < 8; ++ww) {    // redundant merge in all threads
      float ov = pv[ww]; int oi = pi[ww];
      if (ov > fv || (ov == fv && oi < fi)) { fv = ov; fi = oi; }
    }
    if (t == 0) {
      float* o = newxyz + ((size_t)b * SS + it) * 3;
      o[0] = xb[3 * fi]; o[1] = xb[3 * fi + 1]; o[2] = xb[3 * fi + 2];
    }
  }
}

// ---------------------------------------------------------------------------
// 2) Ball query + gather (fused): one wave per centroid, ascending-index scan
//    with ballot == ref's sort+slice. feat is channel-major [6][PTOT].
// ---------------------------------------------------------------------------
__global__ __launch_bounds__(256, 2)
void ballq_kernel(const float* __restrict__ xyz, const float* __restrict__ pts,
                  const float* __restrict__ newxyz, float* __restrict__ feat) {
  const int lane = threadIdx.x & 63;
  const int c = blockIdx.x * 4 + (threadIdx.x >> 6);  // 0..8191
  const int b = c >> 10;
  const float* xb = xyz + (size_t)b * NPT * 3;
  const float* pb = pts + (size_t)b * NPT * 3;
  const float cx = newxyz[3 * c], cy = newxyz[3 * c + 1], cz = newxyz[3 * c + 2];
  const int base = c * KSAMP;
  const uint64_t ltm = (1ull << lane) - 1ull;

  int cnt = 0, firstp = 0;
  bool haveFirst = false;
  for (int p0 = 0; p0 < NPT && cnt < KSAMP; p0 += 64) {
    int p = p0 + lane;
    float px = xb[3 * p], py = xb[3 * p + 1], pz = xb[3 * p + 2];
    float dx = cx - px, dy = cy - py, dz = cz - pz;
    float sqr = (dx * dx + dy * dy) + dz * dz;
    bool in = (sqr <= R2);                          // !(sqr > r^2)
    uint64_t m = __ballot(in);
    if (!haveFirst && m) { firstp = p0 + (__ffsll((unsigned long long)m) - 1); haveFirst = true; }
    int rank = (int)__popcll(m & ltm);
    int slot = cnt + rank;
    if (in && slot < KSAMP) {
      int idx = base + slot;
      feat[0 * PTOT + idx] = px - cx;
      feat[1 * PTOT + idx] = py - cy;
      feat[2 * PTOT + idx] = pz - cz;
      feat[3 * PTOT + idx] = pb[3 * p];
      feat[4 * PTOT + idx] = pb[3 * p + 1];
      feat[5 * PTOT + idx] = pb[3 * p + 2];
    }
    cnt += (int)__popcll(m);
  }
  if (cnt < KSAMP) {  // pad with first in-ball point (center itself qualifies)
    int slot = cnt + lane;
    if (slot < KSAMP) {
      int idx = base + slot;
      float px = xb[3 * firstp], py = xb[3 * firstp + 1], pz = xb[3 * firstp + 2];
      feat[0 * PTOT + idx] = px - cx;
      feat[1 * PTOT + idx] = py - cy;
      feat[2 * PTOT + idx] = pz - cz;
      feat[3 * PTOT + idx] = pb[3 * firstp];
      feat[4 * PTOT + idx] = pb[3 * firstp + 1];
      feat[5 * PTOT + idx] = pb[3 * firstp + 2];
    }
  }
}

// ---------------------------------------------------------------------------
// 3) stats of layer-1 pre-activations. Per-thread s[64],q[64] (cheap here:
//    only 6 FMA per channel). Block-reduce -> global atomics.
// ---------------------------------------------------------------------------
__global__ __launch_bounds__(256, 2)
void mlp1s_kernel(const float* __restrict__ feat, const float* __restrict__ w0,
                  const float* __restrict__ b0, float* __restrict__ stats) {
  float s[64], q[64];
#pragma unroll
  for (int o = 0; o < 64; ++o) { s[o] = 0.0f; q[o] = 0.0f; }
  int gid = blockIdx.x * 256 + threadIdx.x;
  for (int p = gid; p < PTOT; p += 256 * 256) {
    float f[6];
#pragma unroll
    for (int ch = 0; ch < 6; ++ch) f[ch] = feat[ch * PTOT + p];
#pragma unroll
    for (int o = 0; o < 64; ++o) {
      float z = b0[o];
#pragma unroll
      for (int i = 0; i < 6; ++i) z = fmaf(w0[o * 6 + i], f[i], z);
      s[o] += z; q[o] = fmaf(z, z, q[o]);
    }
  }
  const int lane = threadIdx.x & 63;
#pragma unroll
  for (int o = 0; o < 64; ++o) { s[o] = wave_sum(s[o]); q[o] = wave_sum(q[o]); }
  __shared__ float ls[128];
  if (threadIdx.x < 128) ls[threadIdx.x] = 0.0f;
  __syncthreads();
  if (lane == 0) {
#pragma unroll
    for (int o = 0; o < 64; ++o) { atomicAdd(&ls[o], s[o]); atomicAdd(&ls[64 + o], q[o]); }
  }
  __syncthreads();
  if (threadIdx.x < 64) atomicAdd(&stats[OFF_S1 + threadIdx.x], ls[threadIdx.x]);
  else if (threadIdx.x < 128) atomicAdd(&stats[OFF_Q1 + threadIdx.x - 64], ls[threadIdx.x]);
}

// ---------------------------------------------------------------------------
// BN fold: a = g/sqrt(var+eps), c = be - a*mu   (h = relu(a*z + c))
// ---------------------------------------------------------------------------
__global__ void fin_kernel(const float* __restrict__ g, const float* __restrict__ be,
                           const float* __restrict__ s, const float* __restrict__ q,
                           float* __restrict__ A, float* __restrict__ C, int Cn) {
  int o = blockIdx.x * blockDim.x + threadIdx.x;
  if (o >= Cn) return;
  float mu = s[o] * INV_M;
  float var = q[o] * INV_M - mu * mu;
  float a = g[o] / sqrtf(var + EPSBN);
  A[o] = a;
  C[o] = be[o] - a * mu;
}

// ---------------------------------------------------------------------------
// 4) stats of layer-2 pre-activations. h1 built explicitly (unrolled o),
//    then rolled-o loop: scalar z2 accumulators + wave-butterfly stats into
//    designated-lane registers.
// ---------------------------------------------------------------------------
__global__ __launch_bounds__(256, 2)
void mlp2s_kernel(const float* __restrict__ feat,
                  const float* __restrict__ w0, const float* __restrict__ b0,
                  const float* __restrict__ w1, const float* __restrict__ b1,
                  const float* __restrict__ par, float* __restrict__ stats) {
  const float* a1 = par + OFF_A1;
  const float* c1 = par + OFF_C1;
  const int lane = threadIdx.x & 63;
  float sp = 0.0f, qp = 0.0f;          // this lane's channel (== lane)
  int gid = blockIdx.x * 256 + threadIdx.x;
  for (int p = gid; p < PTOT; p += 512 * 256) {
    float f[6];
#pragma unroll
    for (int ch = 0; ch < 6; ++ch) f[ch] = feat[ch * PTOT + p];
    float h1[64];
#pragma unroll
    for (int o = 0; o < 64; ++o) {
      float z = b0[o];
#pragma unroll
      for (int i = 0; i < 6; ++i) z = fmaf(w0[o * 6 + i], f[i], z);
      h1[o] = fmaxf(fmaf(a1[o], z, c1[o]), 0.0f);
    }
    for (int o = 0; o < 64; o += 2) {   // rolled: scalar temps only
      float z0 = b1[o], z1 = b1[o + 1];
#pragma unroll
      for (int i = 0; i < 64; ++i) {
        z0 = fmaf(w1[o * 64 + i], h1[i], z0);
        z1 = fmaf(w1[(o + 1) * 64 + i], h1[i], z1);
      }
      float s0 = wave_sum(z0), q0 = wave_sum(z0 * z0);
      float s1 = wave_sum(z1), q1 = wave_sum(z1 * z1);
      if (lane == o)     { sp += s0; qp += q0; }
      if (lane == o + 1) { sp += s1; qp += q1; }
    }
  }
  atomicAdd(&stats[OFF_S2 + lane], sp);
  atomicAdd(&stats[OFF_Q2 + lane], qp);
}

// ---------------------------------------------------------------------------
// 5) layer-3 fused: recompute h1 (per-i, no array), accumulate h2[64]
//    (i-rolled, o-unrolled), then rolled-o layer-3 with butterfly stats +
//    half-wave max. Writes zmax[g][o] (raw pre-BN max; valid because a3>0
//    makes relu(a*z+c) monotone).
// ---------------------------------------------------------------------------
__global__ __launch_bounds__(256, 2)
void mlp3f_kernel(const float* __restrict__ feat,
                  const float* __restrict__ w0, const float* __restrict__ b0,
                  const float* __restrict__ w1, const float* __restrict__ b1,
                  const float* __restrict__ w2, const float* __restrict__ b2,
                  const float* __restrict__ par, float* __restrict__ stats,
                  float* __restrict__ zmax) {
  const float* a1 = par + OFF_A1;
  const float* c1 = par + OFF_C1;
  const float* a2 = par + OFF_A2;
  const float* c2 = par + OFF_C2;
  const int lane = threadIdx.x & 63;
  float sp0 = 0.0f, qp0 = 0.0f;        // channel lane
  float sp1 = 0.0f, qp1 = 0.0f;        // channel 64+lane
  int gid = blockIdx.x * 256 + threadIdx.x;
  for (int p = gid; p < PTOT; p += 512 * 256) {
    float f[6];
#pragma unroll
    for (int ch = 0; ch < 6; ++ch) f[ch] = feat[ch * PTOT + p];
    float h2[64];
#pragma unroll
    for (int o = 0; o < 64; ++o) h2[o] = b1[o];
    for (int i = 0; i < 64; ++i) {      // rolled; h1[i] recomputed (8 instr)
      float z = b0[i];
#pragma unroll
      for (int ch = 0; ch < 6; ++ch) z = fmaf(w0[i * 6 + ch], f[ch], z);
      float h1i = fmaxf(fmaf(a1[i], z, c1[i]), 0.0f);
#pragma unroll
      for (int o = 0; o < 64; ++o) h2[o] = fmaf(w1[o * 64 + i], h1i, h2[o]);
    }
#pragma unroll
    for (int o = 0; o < 64; ++o) h2[o] = fmaxf(fmaf(a2[o], h2[o], c2[o]), 0.0f);

    const int g = p >> 5;               // this lane's group
    for (int o = 0; o < 128; o += 2) {  // rolled: scalar temps
      float z0 = b2[o], z1 = b2[o + 1];
#pragma unroll
      for (int i = 0; i < 64; ++i) {
        z0 = fmaf(w2[o * 64 + i], h2[i], z0);
        z1 = fmaf(w2[(o + 1) * 64 + i], h2[i], z1);
      }
      float s0 = wave_sum(z0), q0 = wave_sum(z0 * z0);
      float s1 = wave_sum(z1), q1 = wave_sum(z1 * z1);
      if (lane == (o & 63))       { if (o < 64) { sp0 += s0; qp0 += q0; } else { sp1 += s0; qp1 += q0; } }
      if (lane == ((o + 1) & 63)) { if (o < 64) { sp0 += s1; qp0 += q1; } else { sp1 += s1; qp1 += q1; } }
      float m0 = half_max(z0), m1 = half_max(z1);
      if ((lane & 31) == (o & 31))       zmax[g * 128 + o]     = m0;
      if ((lane & 31) == ((o + 1) & 31)) zmax[g * 128 + o + 1] = m1;
    }
  }
  atomicAdd(&stats[OFF_S3 + lane], sp0);
  atomicAdd(&stats[OFF_Q3 + lane], qp0);
  atomicAdd(&stats[OFF_S3 + 64 + lane], sp1);
  atomicAdd(&stats[OFF_Q3 + 64 + lane], qp1);
}

// ---------------------------------------------------------------------------
// 6) epilogue: out2[g][c] = relu(a3[c]*zmax[g][c] + c3[c])
// ---------------------------------------------------------------------------
__global__ __launch_bounds__(256, 4)
void final_out_kernel(const float* __restrict__ zmax, const float* __restrict__ par,
                      float* __restrict__ out2) {
  const float* a3 = par + OFF_A3;
  const float* c3 = par + OFF_C3;
  int idx = blockIdx.x * 256 + threadIdx.x;   // g*128 + c
  int c = idx & 127;
  out2[idx] = fmaxf(fmaf(a3[c], zmax[idx], c3[c]), 0.0f);
}

// ---------------------------------------------------------------------------
extern "C" void kernel_launch(void* const* d_in, const int* in_sizes, int n_in,
                              void* d_out, int out_size, void* d_ws, size_t ws_size,
                              hipStream_t stream) {
  const float* xyz = (const float*)d_in[0];
  const float* pts = (const float*)d_in[1];
  const float* w0  = (const float*)d_in[2];
  const float* b0  = (const float*)d_in[3];
  const float* g0  = (const float*)d_in[4];
  const float* be0 = (const float*)d_in[5];
  const float* w1  = (const float*)d_in[6];
  const float* b1  = (const float*)d_in[7];
  const float* g1  = (const float*)d_in[8];
  const float* be1 = (const float*)d_in[9];
  const float* w2  = (const float*)d_in[10];
  const float* b2  = (const float*)d_in[11];
  const float* g2  = (const float*)d_in[12];
  const float* be2 = (const float*)d_in[13];

  float* out  = (float*)d_out;
  float* nxz  = out;                 // (B,S,3)
  float* out2 = out + BB * SS * 3;   // (B,S,128)

  float* ws    = (float*)d_ws;
  float* stats = ws;                 // 512 floats, zeroed every call
  float* par   = ws;                 // params addressed via OFF_* macros
  float* zmax  = ws + OFF_ZMAX;
  float* feat  = ws + OFF_FEAT;
  float4* bpt  = (float4*)(ws + OFF_FEAT);  // fps scratch, freed before ballq

  hipMemsetAsync(stats, 0, 512 * sizeof(float), stream);

  fps_kernel<<<BB, 1024, 0, stream>>>(xyz, nxz, bpt);
  ballq_kernel<<<2048, 256, 0, stream>>>(xyz, pts, nxz, feat);

  mlp1s_kernel<<<256, 256, 0, stream>>>(feat, w0, b0, stats);
  fin_kernel<<<1, 64, 0, stream>>>(g0, be0, stats + OFF_S1, stats + OFF_Q1,
                                   par + OFF_A1, par + OFF_C1, 64);
  mlp2s_kernel<<<512, 256, 0, stream>>>(feat, w0, b0, w1, b1, par, stats);
  fin_kernel<<<1, 64, 0, stream>>>(g1, be1, stats + OFF_S2, stats + OFF_Q2,
                                   par + OFF_A2, par + OFF_C2, 64);
  mlp3f_kernel<<<512, 256, 0, stream>>>(feat, w0, b0, w1, b1, w2, b2, par, stats, zmax);
  fin_kernel<<<1, 128, 0, stream>>>(g2, be2, stats + OFF_S3, stats + OFF_Q3,
                                    par + OFF_A3, par + OFF_C3, 128);
  final_out_kernel<<<4096, 256, 0, stream>>>(zmax, par, out2);
}